// Round 4
// baseline (597.131 us; speedup 1.0000x reference)
//
#include <hip/hip_runtime.h>

#define N_DIM 8192
#define E_DIM 4096
#define NT    64   // K-tiles of 64

using short8 = __attribute__((ext_vector_type(8))) short;
using f32x4  = __attribute__((ext_vector_type(4))) float;

__device__ __forceinline__ unsigned short f2bf(float f) {
  union { float f; unsigned int u; } v; v.f = f;
  unsigned int r = v.u + 0x7FFFu + ((v.u >> 16) & 1u);
  return (unsigned short)(r >> 16);
}

__device__ __forceinline__ void async16(const void* g, void* l) {
  __builtin_amdgcn_global_load_lds(
      (const __attribute__((address_space(1))) unsigned int*)g,
      (__attribute__((address_space(3))) unsigned int*)l, 16, 0, 0);
}

// ---------------- kernel 1: d = rsqrt(H @ W), one wave per row ----------------
__global__ __launch_bounds__(256) void k_rowdeg(const float* __restrict__ H,
                                                const float* __restrict__ W,
                                                float* __restrict__ d) {
  const int row  = blockIdx.x * 4 + (threadIdx.x >> 6);
  const int lane = threadIdx.x & 63;
  const float* hrow = H + (size_t)row * E_DIM;
  float s = 0.f;
  for (int e = lane * 4; e < E_DIM; e += 64 * 4) {
    float4 h = *reinterpret_cast<const float4*>(hrow + e);
    float4 w = *reinterpret_cast<const float4*>(W + e);
    s += h.x * w.x + h.y * w.y + h.z * w.z + h.w * w.w;
  }
#pragma unroll
  for (int off = 32; off; off >>= 1) s += __shfl_down(s, off);
  if (lane == 0) d[row] = rsqrtf(s);
}

// ---------------- kernel 2: A_bf16[i][e] = bf16(d_i * H[i][e]) ----------------
__global__ __launch_bounds__(256) void k_makeA(const float* __restrict__ H,
                                               const float* __restrict__ d,
                                               unsigned short* __restrict__ A) {
  const size_t idx = ((size_t)blockIdx.x * 256 + threadIdx.x) * 4;
  const int row = (int)(idx >> 12);
  const float dv = d[row];
  float4 h = *reinterpret_cast<const float4*>(H + idx);
  ushort4 o;
  o.x = f2bf(h.x * dv);
  o.y = f2bf(h.y * dv);
  o.z = f2bf(h.z * dv);
  o.w = f2bf(h.w * dv);
  *reinterpret_cast<ushort4*>(A + idx) = o;
}

// ------- kernel 3: Bt_bf16[j][e] = bf16(W_e * invDE_HT[e][j] * d_j) -------
__global__ __launch_bounds__(256) void k_makeB(const float* __restrict__ R,
                                               const float* __restrict__ W,
                                               const float* __restrict__ d,
                                               unsigned short* __restrict__ Bt) {
  __shared__ float tile[32][33];
  const int j0 = blockIdx.x * 32;
  const int e0 = blockIdx.y * 32;
  const int tx = threadIdx.x;
  const int ty = threadIdx.y;
#pragma unroll
  for (int i = 0; i < 32; i += 8)
    tile[ty + i][tx] = R[(size_t)(e0 + ty + i) * N_DIM + j0 + tx];
  __syncthreads();
  const float we = W[e0 + tx];
#pragma unroll
  for (int i = 0; i < 32; i += 8) {
    const int j = j0 + ty + i;
    float v = tile[tx][ty + i] * we * d[j];
    Bt[(size_t)j * E_DIM + e0 + tx] = f2bf(v);
  }
}

// ---------------- kernel 4: 256x256 MFMA GEMM, C = A @ B^T ----------------
// 512 threads (8 waves), BK=64, 128 KB LDS double-buffered, XOR-swizzled.
// ONE barrier per K-tile: all T+1 staging -> buf cN issued at p0 (no same-buf
// clobber, no mid-tile barrier needed). In-wave pipelining via WAR on reused
// af/bf register arrays; snake order Q00->Q10->Q11->Q01 (28 ds_read/tile).

__device__ __forceinline__ void read_af(const unsigned short* base, const int (&off)[2][2],
                                        short8 (&af)[2][2]) {
#pragma unroll
  for (int m = 0; m < 2; ++m)
#pragma unroll
    for (int k = 0; k < 2; ++k)
      af[m][k] = *(const short8*)(base + off[m][k]);
}

__device__ __forceinline__ void read_bf(const unsigned short* base, const int (&off)[4][2],
                                        short8 (&bf)[4][2]) {
#pragma unroll
  for (int n = 0; n < 4; ++n)
#pragma unroll
    for (int k = 0; k < 2; ++k)
      bf[n][k] = *(const short8*)(base + off[n][k]);
}

__device__ __forceinline__ void mfma_quad(f32x4 (&acc)[2][4], const short8 (&af)[2][2],
                                          const short8 (&bf)[4][2]) {
#pragma unroll
  for (int m = 0; m < 2; ++m)
#pragma unroll
    for (int n = 0; n < 4; ++n)
#pragma unroll
      for (int k = 0; k < 2; ++k)
        acc[m][n] = __builtin_amdgcn_mfma_f32_16x16x32_bf16(af[m][k], bf[n][k], acc[m][n], 0, 0, 0);
}

__global__ __launch_bounds__(512, 2) void k_gemm(const unsigned short* __restrict__ A,
                                                 const unsigned short* __restrict__ B,
                                                 float* __restrict__ C) {
  __shared__ unsigned short lds[65536];  // 128 KB: A [0,32768), B [32768,65536)

  const int bid   = blockIdx.x;          // 1024 blocks, %8==0 -> bijective swizzle
  const int chunk = gridDim.x >> 3;
  const int swz   = (bid & 7) * chunk + (bid >> 3);
  const int tm = swz >> 5, tn = swz & 31;
  const size_t rowBase = (size_t)tm * 256;
  const size_t colBase = (size_t)tn * 256;

  const int t = threadIdx.x, wid = t >> 6, lane = t & 63;
  const int lr = lane & 15, hi = lane >> 4;
  const int swzx = (lr & 7) << 4;

  // staging source pointers: LDS dest linear, global source pre-swizzled (rule #21)
  const unsigned short *pa0[2], *pa1[2], *pb0[2], *pb1[2];
#pragma unroll
  for (int j = 0; j < 2; ++j) {
    const int P  = j * 8192 + wid * 1024 + lane * 16;  // physical byte off in 16KB half
    const int rP = P >> 7;
    const int L  = P ^ ((rP & 7) << 4);                // logical byte off (involution)
    const int ce = (L & 127) >> 1;                     // element col
    pa0[j] = A + (rowBase +       rP) * E_DIM + ce;
    pa1[j] = A + (rowBase + 128 + rP) * E_DIM + ce;
    pb0[j] = B + (colBase +       rP) * E_DIM + ce;
    pb1[j] = B + (colBase + 128 + rP) * E_DIM + ce;
  }
  const int dst = wid * 512;  // shorts; + j*4096 + half-base

#define STG(Pj, base_, kt)                                          \
  do {                                                              \
    async16(Pj[0] + (size_t)(kt) * 64, &lds[(base_) + dst]);        \
    async16(Pj[1] + (size_t)(kt) * 64, &lds[(base_) + 4096 + dst]); \
  } while (0)

  // fragment read offsets (shorts), swizzled
  int offA[2][2], offB[4][2];
#pragma unroll
  for (int m = 0; m < 2; ++m)
#pragma unroll
    for (int k = 0; k < 2; ++k) {
      const int row  = (wid & 3) * 32 + m * 16 + lr;
      const int colb = k * 64 + hi * 16;
      offA[m][k] = (row * 128 + (colb ^ swzx)) >> 1;
    }
#pragma unroll
  for (int n = 0; n < 4; ++n)
#pragma unroll
    for (int k = 0; k < 2; ++k) {
      const int row  = (wid >> 2) * 64 + n * 16 + lr;
      const int colb = k * 64 + hi * 16;
      offB[n][k] = (row * 128 + (colb ^ swzx)) >> 1;
    }

  // ---- prologue: stage tile 0 -> buf0, wait, barrier ----
  STG(pa0, 0, 0);
  STG(pa1, 8192, 0);
  STG(pb0, 32768, 0);
  STG(pb1, 32768 + 8192, 0);
  asm volatile("s_waitcnt vmcnt(0)" ::: "memory");
  __builtin_amdgcn_s_barrier();

  f32x4 acc[2][2][2][4] = {};  // [a][b][m][n]
  short8 af[2][2], bf[4][2];

  for (int T = 0; T < NT; ++T) {
    const int c  = T & 1;
    const int aB = c * 16384;
    const int bB = 32768 + c * 16384;
    const int cN = (T + 1) & 1;
    const int aN = cN * 16384;
    const int bN = 32768 + cN * 16384;

    // ---- p0: Q(0,0) — read af(A0)+bf(B0); stage ALL of tile T+1 -> buf cN ----
    read_af(&lds[aB], offA, af);
    read_bf(&lds[bB], offB, bf);
    if (T + 1 < NT) {
      STG(pa0, aN, T + 1);
      STG(pa1, aN + 8192, T + 1);
      STG(pb0, bN, T + 1);
      STG(pb1, bN + 8192, T + 1);
    }
    __builtin_amdgcn_s_setprio(1);
    mfma_quad(acc[0][0], af, bf);
    __builtin_amdgcn_s_setprio(0);

    // ---- p1: Q(1,0) — read af(A1), reuse bf(B0) ----
    read_af(&lds[aB + 8192], offA, af);
    __builtin_amdgcn_s_setprio(1);
    mfma_quad(acc[1][0], af, bf);
    __builtin_amdgcn_s_setprio(0);

    // ---- p2: Q(1,1) — read bf(B1), reuse af(A1) ----
    read_bf(&lds[bB + 8192], offB, bf);
    __builtin_amdgcn_s_setprio(1);
    mfma_quad(acc[1][1], af, bf);
    __builtin_amdgcn_s_setprio(0);

    // ---- p3: Q(0,1) — read af(A0), reuse bf(B1) ----
    read_af(&lds[aB], offA, af);
    __builtin_amdgcn_s_setprio(1);
    mfma_quad(acc[0][1], af, bf);
    __builtin_amdgcn_s_setprio(0);

    // ---- tile gate: T+1 stages issued ~a full tile ago -> drain is cheap ----
    asm volatile("s_waitcnt vmcnt(0)" ::: "memory");
    __builtin_amdgcn_s_barrier();
  }
#undef STG

  // ---- epilogue: C/D layout col=lane&15, row=(lane>>4)*4+reg ----
#pragma unroll
  for (int a = 0; a < 2; ++a)
#pragma unroll
    for (int b = 0; b < 2; ++b)
#pragma unroll
      for (int m = 0; m < 2; ++m)
#pragma unroll
        for (int n = 0; n < 4; ++n)
#pragma unroll
          for (int r = 0; r < 4; ++r) {
            const size_t row = rowBase + a * 128 + (wid & 3) * 32 + m * 16 + hi * 4 + r;
            const size_t col = colBase + b * 128 + (wid >> 2) * 64 + n * 16 + lr;
            C[row * N_DIM + col] = acc[a][b][m][n][r];
          }
}

extern "C" void kernel_launch(void* const* d_in, const int* in_sizes, int n_in,
                              void* d_out, int out_size, void* d_ws, size_t ws_size,
                              hipStream_t stream) {
  const float* H = (const float*)d_in[0];   // [N, E]
  const float* R = (const float*)d_in[1];   // [E, N]
  const float* W = (const float*)d_in[2];   // [E]
  float* C = (float*)d_out;                 // [N, N]

  char* ws = (char*)d_ws;
  float* d            = (float*)ws;
  unsigned short* Abf = (unsigned short*)(ws + 32768);
  unsigned short* Bbf = (unsigned short*)(ws + 32768 + (size_t)N_DIM * E_DIM * 2);

  k_rowdeg<<<N_DIM / 4, 256, 0, stream>>>(H, W, d);
  k_makeA<<<(int)(((size_t)N_DIM * E_DIM / 4) / 256), 256, 0, stream>>>(H, d, Abf);
  k_makeB<<<dim3(N_DIM / 32, E_DIM / 32), dim3(32, 8), 0, stream>>>(R, W, d, Bbf);
  k_gemm<<<(N_DIM / 256) * (N_DIM / 256), 512, 0, stream>>>(Abf, Bbf, C);
}

// Round 5
// 473.319 us; speedup vs baseline: 1.2616x; 1.2616x over previous
//
#include <hip/hip_runtime.h>

#define N_DIM 8192
#define E_DIM 4096
#define BK    128
#define NT    (E_DIM / BK)   // 32 K-tiles

using int4v  = __attribute__((ext_vector_type(4))) int;
using i32x16 = __attribute__((ext_vector_type(16))) int;

__device__ __forceinline__ void async16(const void* g, void* l) {
  __builtin_amdgcn_global_load_lds(
      (const __attribute__((address_space(1))) unsigned int*)g,
      (__attribute__((address_space(3))) unsigned int*)l, 16, 0, 0);
}

// ---- kernel 1: d = rsqrt(H@W); dmax via atomicMax on nonneg-float bits ----
__global__ __launch_bounds__(256) void k_rowdeg(const float* __restrict__ H,
                                                const float* __restrict__ W,
                                                float* __restrict__ d,
                                                unsigned int* __restrict__ dmax_bits) {
  const int row  = blockIdx.x * 4 + (threadIdx.x >> 6);
  const int lane = threadIdx.x & 63;
  const float* hrow = H + (size_t)row * E_DIM;
  float s = 0.f;
  for (int e = lane * 4; e < E_DIM; e += 256) {
    float4 h = *reinterpret_cast<const float4*>(hrow + e);
    float4 w = *reinterpret_cast<const float4*>(W + e);
    s += h.x * w.x + h.y * w.y + h.z * w.z + h.w * w.w;
  }
#pragma unroll
  for (int off = 32; off; off >>= 1) s += __shfl_down(s, off);
  if (lane == 0) {
    float v = rsqrtf(s);
    d[row] = v;
    atomicMax(dmax_bits, __float_as_uint(v));  // nonneg: uint order == float order
  }
}

// ---- kernel 1b: wmax (single block) ----
__global__ __launch_bounds__(256) void k_wmax(const float* __restrict__ W,
                                              float* __restrict__ wmax) {
  __shared__ float red[4];
  float m = 0.f;
  for (int i = threadIdx.x; i < E_DIM; i += 256) m = fmaxf(m, W[i]);
#pragma unroll
  for (int off = 32; off; off >>= 1) m = fmaxf(m, __shfl_down(m, off));
  if ((threadIdx.x & 63) == 0) red[threadIdx.x >> 6] = m;
  __syncthreads();
  if (threadIdx.x == 0) wmax[0] = fmaxf(fmaxf(red[0], red[1]), fmaxf(red[2], red[3]));
}

// ---- kernel 2: A_i8[i][e] = round(d_i*H[i][e] * 127/dmax)  (in [0,127]) ----
__global__ __launch_bounds__(256) void k_makeA(const float* __restrict__ H,
                                               const float* __restrict__ d,
                                               const float* __restrict__ scal,
                                               signed char* __restrict__ A) {
  const size_t idx = ((size_t)blockIdx.x * 256 + threadIdx.x) * 8;
  const int row = (int)(idx >> 12);
  const float q = d[row] * (127.0f / scal[0]);
  float4 h0 = *reinterpret_cast<const float4*>(H + idx);
  float4 h1 = *reinterpret_cast<const float4*>(H + idx + 4);
  union { signed char c[8]; long l; } o;
  o.c[0] = (signed char)__float2int_rn(h0.x * q);
  o.c[1] = (signed char)__float2int_rn(h0.y * q);
  o.c[2] = (signed char)__float2int_rn(h0.z * q);
  o.c[3] = (signed char)__float2int_rn(h0.w * q);
  o.c[4] = (signed char)__float2int_rn(h1.x * q);
  o.c[5] = (signed char)__float2int_rn(h1.y * q);
  o.c[6] = (signed char)__float2int_rn(h1.z * q);
  o.c[7] = (signed char)__float2int_rn(h1.w * q);
  *reinterpret_cast<long*>(A + idx) = o.l;
}

// ---- kernel 3: Bt_i8[j][e] = round(W_e*R[e][j]*d_j * 127/(dmax*wmax)) ----
__global__ void k_makeB(const float* __restrict__ R, const float* __restrict__ W,
                        const float* __restrict__ d, const float* __restrict__ scal,
                        signed char* __restrict__ Bt) {
  __shared__ float tile[32][33];
  const int j0 = blockIdx.x * 32;
  const int e0 = blockIdx.y * 32;
  const int tx = threadIdx.x, ty = threadIdx.y;
#pragma unroll
  for (int i = 0; i < 32; i += 8)
    tile[ty + i][tx] = R[(size_t)(e0 + ty + i) * N_DIM + j0 + tx];
  __syncthreads();
  const float rsB = 127.0f / (scal[0] * scal[1]);
  const float we = W[e0 + tx] * rsB;
#pragma unroll
  for (int i = 0; i < 32; i += 8) {
    const int j = j0 + ty + i;
    float v = tile[tx][ty + i] * we * d[j];
    Bt[(size_t)j * E_DIM + e0 + tx] = (signed char)__float2int_rn(v);
  }
}

// ---- kernel 4: 256x256 i8 MFMA GEMM (BK=128), C = sAB * (A_i8 @ B_i8^T) ----
// R3-proven skeleton: per phase [reads; STG one half; vmcnt(4); barrier; MFMA].
// XOR swizzle ((row&7)<<4) both-sides (pre-swizzled global src, swizzled reads).
// Seal ledger: STG B0'@p0 (last read p0,T-1), A0'@p1 (p3,T-1), A1'@p2 (p1,T-1),
// B1'@p3 (p2,T-1) -- each >=1 barrier after its region's last ds_read.
// Gate ledger (async16 units, 2/half): uniform vmcnt(4) leaves exactly the 2
// not-yet-needed halves in flight. Tail tile peeled with vmcnt(2)/vmcnt(0).
__global__ __launch_bounds__(512, 2) void k_gemm(const signed char* __restrict__ A,
                                                 const signed char* __restrict__ B,
                                                 const float* __restrict__ scal,
                                                 float* __restrict__ C) {
  __shared__ alignas(16) signed char lds[131072];  // A: 2x32KB, B: 2x32KB

  const int bid   = blockIdx.x;          // 1024 blocks, %8==0 -> bijective swizzle
  const int chunk = gridDim.x >> 3;
  const int swzb  = (bid & 7) * chunk + (bid >> 3);
  const int tm = swzb >> 5, tn = swzb & 31;
  const size_t rowBase = (size_t)tm * 256;
  const size_t colBase = (size_t)tn * 256;

  const int t = threadIdx.x, wid = t >> 6, lane = t & 63;
  const int l31 = lane & 31, hi32 = lane >> 5;

  // staging sources: LDS dest linear, global source pre-swizzled (rule #21)
  const signed char *pA0[2], *pA1[2], *pB0[2], *pB1[2];
#pragma unroll
  for (int j = 0; j < 2; ++j) {
    const int P  = j * 8192 + wid * 1024 + lane * 16;  // byte off in 16KB half
    const int rP = P >> 7;                             // row 0..127
    const int ce = (P ^ ((rP & 7) << 4)) & 127;        // logical elem col (involution)
    pA0[j] = A + (rowBase +       rP) * E_DIM + ce;
    pA1[j] = A + (rowBase + 128 + rP) * E_DIM + ce;
    pB0[j] = B + (colBase +       rP) * E_DIM + ce;
    pB1[j] = B + (colBase + 128 + rP) * E_DIM + ce;
  }
  const int dstw = wid * 1024;

#define STG(Pj, base_, kt)                                            \
  do {                                                                \
    async16(Pj[0] + (size_t)(kt) * BK, &lds[(base_) + dstw]);         \
    async16(Pj[1] + (size_t)(kt) * BK, &lds[(base_) + 8192 + dstw]);  \
  } while (0)

  // fragment read addressing (bytes), swizzled; (row&7)==lane&7 for all frags
  const int rowAoff = ((wid & 3) * 32 + l31) * 128;
  const int rowBoff = ((wid >> 2) * 64 + l31) * 128;
  const int swz = (lane & 7) << 4;
  int colX[4];
#pragma unroll
  for (int k = 0; k < 4; ++k) colX[k] = (k * 32 + hi32 * 16) ^ swz;

  int4v af[4], bf[2][4];
  i32x16 acc[2][2][2] = {};  // [a-half][b-half][n]

#define RD_A(aH, cb)                                                            \
  do {                                                                          \
    _Pragma("unroll") for (int k = 0; k < 4; ++k)                               \
      af[k] = *(const int4v*)&lds[(cb) * 32768 + (aH) * 16384 + rowAoff + colX[k]]; \
  } while (0)
#define RD_B(bH, cb)                                                            \
  do {                                                                          \
    _Pragma("unroll") for (int n = 0; n < 2; ++n)                               \
      _Pragma("unroll") for (int k = 0; k < 4; ++k)                             \
        bf[n][k] = *(const int4v*)&lds[65536 + (cb) * 32768 + (bH) * 16384 +    \
                                       rowBoff + n * 4096 + colX[k]];           \
  } while (0)
#define MM(a_, b_)                                                              \
  do {                                                                          \
    __builtin_amdgcn_s_setprio(1);                                              \
    _Pragma("unroll") for (int n = 0; n < 2; ++n)                               \
      _Pragma("unroll") for (int k = 0; k < 4; ++k)                             \
        acc[a_][b_][n] =                                                        \
            __builtin_amdgcn_mfma_i32_32x32x32_i8(af[k], bf[n][k],              \
                                                  acc[a_][b_][n], 0, 0, 0);     \
    __builtin_amdgcn_s_setprio(0);                                              \
  } while (0)
#define GATE(n_) asm volatile("s_waitcnt vmcnt(" #n_ ")" ::: "memory")

  // ---- prologue: stage tile 0 (A0,B0,A1,B1 -> buf0); A0,B0 landed before reads ----
  STG(pA0, 0, 0);
  STG(pB0, 65536, 0);
  STG(pA1, 16384, 0);
  STG(pB1, 65536 + 16384, 0);
  GATE(4);
  __builtin_amdgcn_s_barrier();

  for (int T = 0; T < NT - 1; ++T) {
    const int c = T & 1, cN = c ^ 1;
    const int aN = cN * 32768, bN = 65536 + cN * 32768;

    // p0: Q(a0,b0) — reads A0,B0; stage B0(T+1)
    RD_A(0, c);
    RD_B(0, c);
    STG(pB0, bN, T + 1);
    GATE(4);
    __builtin_amdgcn_s_barrier();
    MM(0, 0);

    // p1: Q(a1,b0) — reads A1 (reuse bf); stage A0(T+1)
    RD_A(1, c);
    STG(pA0, aN, T + 1);
    GATE(4);
    __builtin_amdgcn_s_barrier();
    MM(1, 0);

    // p2: Q(a1,b1) — reads B1 (reuse af); stage A1(T+1)
    RD_B(1, c);
    STG(pA1, aN + 16384, T + 1);
    GATE(4);
    __builtin_amdgcn_s_barrier();
    MM(1, 1);

    // p3: Q(a0,b1) — reads A0 (reuse bf); stage B1(T+1)
    RD_A(0, c);
    STG(pB1, bN + 16384, T + 1);
    GATE(4);
    __builtin_amdgcn_s_barrier();
    MM(0, 1);
  }

  // ---- tail tile (T = NT-1, buf c = (NT-1)&1 = 1): no staging, tight gates ----
  {
    RD_A(0, 1);
    RD_B(0, 1);
    GATE(2);
    __builtin_amdgcn_s_barrier();
    MM(0, 0);
    RD_A(1, 1);
    GATE(0);
    __builtin_amdgcn_s_barrier();
    MM(1, 0);
    RD_B(1, 1);
    MM(1, 1);
    RD_A(0, 1);
    MM(0, 1);
  }
#undef STG
#undef RD_A
#undef RD_B
#undef MM
#undef GATE

  // ---- epilogue: 32x32 C/D layout col=lane&31, row=(r&3)+8*(r>>2)+4*(lane>>5) ----
  const float sAB = scal[0] * scal[0] * scal[1] * (1.0f / (127.0f * 127.0f));
#pragma unroll
  for (int a = 0; a < 2; ++a)
#pragma unroll
    for (int b = 0; b < 2; ++b)
#pragma unroll
      for (int n = 0; n < 2; ++n)
#pragma unroll
        for (int r = 0; r < 16; ++r) {
          const size_t row = rowBase + a * 128 + (wid & 3) * 32 + (r & 3) + 8 * (r >> 2) + 4 * hi32;
          const size_t col = colBase + b * 128 + (wid >> 2) * 64 + n * 32 + l31;
          C[row * N_DIM + col] = sAB * (float)acc[a][b][n][r];
        }
}

extern "C" void kernel_launch(void* const* d_in, const int* in_sizes, int n_in,
                              void* d_out, int out_size, void* d_ws, size_t ws_size,
                              hipStream_t stream) {
  const float* H = (const float*)d_in[0];   // [N, E]
  const float* R = (const float*)d_in[1];   // [E, N]
  const float* W = (const float*)d_in[2];   // [E]
  float* C = (float*)d_out;                 // [N, N]

  char* ws = (char*)d_ws;
  float* scal = (float*)ws;                       // [0]=dmax, [1]=wmax
  float* d    = (float*)(ws + 256);               // 32 KB
  signed char* Ai = (signed char*)(ws + 65536);   // 32 MB
  signed char* Bi = Ai + (size_t)N_DIM * E_DIM;   // 32 MB

  hipMemsetAsync(ws, 0, 256, stream);
  k_rowdeg<<<N_DIM / 4, 256, 0, stream>>>(H, W, d, (unsigned int*)scal);
  k_wmax<<<1, 256, 0, stream>>>(W, scal + 1);
  k_makeA<<<(int)(((size_t)N_DIM * E_DIM / 8) / 256), 256, 0, stream>>>(H, d, scal, Ai);
  k_makeB<<<dim3(N_DIM / 32, E_DIM / 32), dim3(32, 8), 0, stream>>>(R, W, d, scal, Bi);
  k_gemm<<<(N_DIM / 256) * (N_DIM / 256), 512, 0, stream>>>(Ai, Bi, scal, C);
}

// Round 6
// 442.913 us; speedup vs baseline: 1.3482x; 1.0687x over previous
//
#include <hip/hip_runtime.h>

#define N_DIM 8192
#define E_DIM 4096
#define BK    128
#define NT    (E_DIM / BK)   // 32 K-tiles

using int4v  = __attribute__((ext_vector_type(4))) int;
using i32x16 = __attribute__((ext_vector_type(16))) int;

__device__ __forceinline__ void async16(const void* g, void* l) {
  __builtin_amdgcn_global_load_lds(
      (const __attribute__((address_space(1))) unsigned int*)g,
      (__attribute__((address_space(3))) unsigned int*)l, 16, 0, 0);
}

// ---- kernel 1: fused degree + per-row quantize of A ----
// wave per row; row kept in 16xfloat4 regs (H read ONCE).
// qA = round(H * 127/m_i)  (d_i cancels); sA_i = d_i*m_i/127.
__global__ __launch_bounds__(256) void k_prepA(const float* __restrict__ H,
                                               const float* __restrict__ W,
                                               float* __restrict__ d,
                                               float* __restrict__ sA,
                                               unsigned int* __restrict__ dmax_bits,
                                               signed char* __restrict__ A) {
  const int row  = blockIdx.x * 4 + (threadIdx.x >> 6);
  const int lane = threadIdx.x & 63;
  const float* hrow = H + (size_t)row * E_DIM;
  float4 h[16];
  float s = 0.f, m = 0.f;
#pragma unroll
  for (int i = 0; i < 16; ++i) {
    h[i] = *reinterpret_cast<const float4*>(hrow + lane * 4 + i * 256);
    float4 w = *reinterpret_cast<const float4*>(W + lane * 4 + i * 256);
    s += h[i].x * w.x + h[i].y * w.y + h[i].z * w.z + h[i].w * w.w;
    m = fmaxf(m, fmaxf(fmaxf(h[i].x, h[i].y), fmaxf(h[i].z, h[i].w)));
  }
#pragma unroll
  for (int off = 1; off < 64; off <<= 1) {
    s += __shfl_xor(s, off);
    m = fmaxf(m, __shfl_xor(m, off));
  }
  const float dv = rsqrtf(s);
  if (lane == 0) {
    d[row]  = dv;
    sA[row] = dv * m * (1.0f / 127.0f);
    atomicMax(dmax_bits, __float_as_uint(dv));  // nonneg: uint order == float order
  }
  const float q = 127.0f / m;
  signed char* arow = A + (size_t)row * E_DIM;
#pragma unroll
  for (int i = 0; i < 16; ++i) {
    const int b0 = __float2int_rn(h[i].x * q);
    const int b1 = __float2int_rn(h[i].y * q);
    const int b2 = __float2int_rn(h[i].z * q);
    const int b3 = __float2int_rn(h[i].w * q);
    const unsigned int pk = (unsigned)b0 | ((unsigned)b1 << 8) |
                            ((unsigned)b2 << 16) | ((unsigned)b3 << 24);
    *reinterpret_cast<unsigned int*>(arow + lane * 4 + i * 256) = pk;
  }
}

// ---- kernel 1b: wmax (single block) ----
__global__ __launch_bounds__(256) void k_wmax(const float* __restrict__ W,
                                              float* __restrict__ wmax) {
  __shared__ float red[4];
  float m = 0.f;
  for (int i = threadIdx.x; i < E_DIM; i += 256) m = fmaxf(m, W[i]);
#pragma unroll
  for (int off = 32; off; off >>= 1) m = fmaxf(m, __shfl_down(m, off));
  if ((threadIdx.x & 63) == 0) red[threadIdx.x >> 6] = m;
  __syncthreads();
  if (threadIdx.x == 0) wmax[0] = fmaxf(fmaxf(red[0], red[1]), fmaxf(red[2], red[3]));
}

// ---- kernel 3: coalesced transpose-quantize: Bt_i8[j][e] = q(W_e*R[e][j]*d_j) ----
// 128e x 128j tile; float4 reads (1KB/wave), LDS [128][132] (write conflict-free,
// transpose-read 2-way=free), 64B-contiguous i8 writes per j-row.
__global__ __launch_bounds__(256) void k_makeB(const float* __restrict__ R,
                                               const float* __restrict__ W,
                                               const float* __restrict__ d,
                                               const float* __restrict__ scal,
                                               signed char* __restrict__ Bt) {
  __shared__ float ft[128][132];
  const int j0 = blockIdx.x * 128;
  const int e0 = blockIdx.y * 128;
  const int t = threadIdx.x;
  const int c4 = (t & 31) * 4;
#pragma unroll
  for (int r = (t >> 5); r < 128; r += 8) {
    float4 v = *reinterpret_cast<const float4*>(&R[(size_t)(e0 + r) * N_DIM + j0 + c4]);
    *reinterpret_cast<float4*>(&ft[r][c4]) = v;
  }
  __syncthreads();
  const int jl = t & 127;
  const int h  = t >> 7;                 // e-half 0/1
  const int j  = j0 + jl;
  const float rsB = 127.0f / (scal[0] * scal[1]);
  const float dj  = d[j] * rsB;
  union { signed char c[64]; int4v i4[4]; } o;
#pragma unroll
  for (int e = 0; e < 64; ++e) {
    const int ee = h * 64 + e;
    o.c[e] = (signed char)__float2int_rn(ft[ee][jl] * W[e0 + ee] * dj);
  }
  signed char* dstp = Bt + (size_t)j * E_DIM + e0 + h * 64;
#pragma unroll
  for (int s2 = 0; s2 < 4; ++s2)
    *reinterpret_cast<int4v*>(dstp + s2 * 16) = o.i4[s2];
}

// ---- kernel 4: 256x256 i8 MFMA GEMM (BK=128), C = sA[i]*tB * (A_i8 @ B_i8^T) ----
// R3-proven phase skeleton [RD; STG; vmcnt(4); barrier; MM]; af0/af1 persistent
// (24 ds_read_b128/wave/tile). Seal: each staged region's last reader is >=4
// barriers before its STG. Gate: uniform vmcnt(4) = 2 halves in flight.
__global__ __launch_bounds__(512, 2) void k_gemm(const signed char* __restrict__ A,
                                                 const signed char* __restrict__ B,
                                                 const float* __restrict__ scal,
                                                 const float* __restrict__ sA,
                                                 float* __restrict__ C) {
  __shared__ alignas(16) signed char lds[131072];  // A: 2x32KB, B: 2x32KB

  const int bid   = blockIdx.x;          // 1024 blocks, %8==0 -> bijective swizzle
  const int chunk = gridDim.x >> 3;
  const int swzb  = (bid & 7) * chunk + (bid >> 3);
  const int tm = swzb >> 5, tn = swzb & 31;
  const size_t rowBase = (size_t)tm * 256;
  const size_t colBase = (size_t)tn * 256;

  const int t = threadIdx.x, wid = t >> 6, lane = t & 63;
  const int l31 = lane & 31, hi32 = lane >> 5;

  const signed char *pA0[2], *pA1[2], *pB0[2], *pB1[2];
#pragma unroll
  for (int j = 0; j < 2; ++j) {
    const int P  = j * 8192 + wid * 1024 + lane * 16;  // byte off in 16KB half
    const int rP = P >> 7;                             // row 0..127
    const int ce = (P ^ ((rP & 7) << 4)) & 127;        // pre-swizzled source col
    pA0[j] = A + (rowBase +       rP) * E_DIM + ce;
    pA1[j] = A + (rowBase + 128 + rP) * E_DIM + ce;
    pB0[j] = B + (colBase +       rP) * E_DIM + ce;
    pB1[j] = B + (colBase + 128 + rP) * E_DIM + ce;
  }
  const int dstw = wid * 1024;

#define STG(Pj, base_, kt)                                            \
  do {                                                                \
    async16(Pj[0] + (size_t)(kt) * BK, &lds[(base_) + dstw]);         \
    async16(Pj[1] + (size_t)(kt) * BK, &lds[(base_) + 8192 + dstw]);  \
  } while (0)

  const int rowAoff = ((wid & 3) * 32 + l31) * 128;
  const int rowBoff = ((wid >> 2) * 64 + l31) * 128;
  const int swz = (lane & 7) << 4;
  int colX[4];
#pragma unroll
  for (int k = 0; k < 4; ++k) colX[k] = (k * 32 + hi32 * 16) ^ swz;

  int4v af0[4], af1[4], bf[2][4];
  i32x16 acc[2][2][2] = {};  // [a-half][b-half][n]

#define RD_A(dst_, aH, cb)                                                        \
  do {                                                                            \
    _Pragma("unroll") for (int k = 0; k < 4; ++k)                                 \
      dst_[k] = *(const int4v*)&lds[(cb) * 32768 + (aH) * 16384 + rowAoff + colX[k]]; \
  } while (0)
#define RD_B(bH, cb)                                                              \
  do {                                                                            \
    _Pragma("unroll") for (int n = 0; n < 2; ++n)                                 \
      _Pragma("unroll") for (int k = 0; k < 4; ++k)                               \
        bf[n][k] = *(const int4v*)&lds[65536 + (cb) * 32768 + (bH) * 16384 +      \
                                       rowBoff + n * 4096 + colX[k]];             \
  } while (0)
#define MM(src_, a_, b_)                                                          \
  do {                                                                            \
    __builtin_amdgcn_s_setprio(1);                                                \
    _Pragma("unroll") for (int n = 0; n < 2; ++n)                                 \
      _Pragma("unroll") for (int k = 0; k < 4; ++k)                               \
        acc[a_][b_][n] =                                                          \
            __builtin_amdgcn_mfma_i32_32x32x32_i8(src_[k], bf[n][k],              \
                                                  acc[a_][b_][n], 0, 0, 0);       \
    __builtin_amdgcn_s_setprio(0);                                                \
  } while (0)
#define GATE(n_) asm volatile("s_waitcnt vmcnt(" #n_ ")" ::: "memory")

  // ---- prologue: stage tile 0 -> buf0; gate(4) => A0,B0 landed ----
  STG(pA0, 0, 0);
  STG(pB0, 65536, 0);
  STG(pA1, 16384, 0);
  STG(pB1, 65536 + 16384, 0);
  GATE(4);
  __builtin_amdgcn_s_barrier();

  for (int T = 0; T < NT - 1; ++T) {
    const int c = T & 1, cN = c ^ 1;
    const int aN = cN * 32768, bN = 65536 + cN * 32768;

    // p0: reads A0,B0; stage B0(T+1); gate => A1 landed
    RD_A(af0, 0, c);
    RD_B(0, c);
    STG(pB0, bN, T + 1);
    GATE(4);
    __builtin_amdgcn_s_barrier();
    MM(af0, 0, 0);

    // p1: reads A1; stage A0(T+1); gate => B1 landed
    RD_A(af1, 1, c);
    STG(pA0, aN, T + 1);
    GATE(4);
    __builtin_amdgcn_s_barrier();
    MM(af1, 1, 0);

    // p2: reads B1; stage A1(T+1); gate => B0(T+1) landed
    RD_B(1, c);
    STG(pA1, aN + 16384, T + 1);
    GATE(4);
    __builtin_amdgcn_s_barrier();
    MM(af1, 1, 1);

    // p3: no reads; stage B1(T+1); gate => A0(T+1) landed
    STG(pB1, bN + 16384, T + 1);
    GATE(4);
    __builtin_amdgcn_s_barrier();
    MM(af0, 0, 1);
  }

  // ---- tail tile (buf 1): outstanding = A1,B1 of this tile ----
  {
    RD_A(af0, 0, 1);
    RD_B(0, 1);
    MM(af0, 0, 0);
    GATE(2);
    RD_A(af1, 1, 1);
    MM(af1, 1, 0);
    GATE(0);
    RD_B(1, 1);
    MM(af1, 1, 1);
    MM(af0, 0, 1);
  }
#undef STG
#undef RD_A
#undef RD_B
#undef MM
#undef GATE

  // ---- epilogue: C = sA[row] * tB * acc ; 32x32 C/D layout ----
  const float tB = scal[0] * scal[1] * (1.0f / 127.0f);
#pragma unroll
  for (int a = 0; a < 2; ++a)
#pragma unroll
    for (int b = 0; b < 2; ++b)
#pragma unroll
      for (int n = 0; n < 2; ++n)
#pragma unroll
        for (int r = 0; r < 16; ++r) {
          const size_t row = rowBase + a * 128 + (wid & 3) * 32 + (r & 3) + 8 * (r >> 2) + 4 * hi32;
          const size_t col = colBase + b * 128 + (wid >> 2) * 64 + n * 32 + l31;
          C[row * N_DIM + col] = sA[row] * tB * (float)acc[a][b][n][r];
        }
}

extern "C" void kernel_launch(void* const* d_in, const int* in_sizes, int n_in,
                              void* d_out, int out_size, void* d_ws, size_t ws_size,
                              hipStream_t stream) {
  const float* H = (const float*)d_in[0];   // [N, E]
  const float* R = (const float*)d_in[1];   // [E, N]
  const float* W = (const float*)d_in[2];   // [E]
  float* C = (float*)d_out;                 // [N, N]

  char* ws = (char*)d_ws;
  float* scal = (float*)ws;                          // [0]=dmax(bits), [1]=wmax
  float* d    = (float*)(ws + 1024);                 // 32 KB
  float* sA   = (float*)(ws + 1024 + 32768);         // 32 KB
  signed char* Ai = (signed char*)(ws + 131072);     // 32 MB
  signed char* Bi = Ai + (size_t)N_DIM * E_DIM;      // 32 MB

  hipMemsetAsync(ws, 0, 256, stream);
  k_prepA<<<N_DIM / 4, 256, 0, stream>>>(H, W, d, sA, (unsigned int*)scal, Ai);
  k_wmax<<<1, 256, 0, stream>>>(W, scal + 1);
  k_makeB<<<dim3(N_DIM / 128, E_DIM / 128), 256, 0, stream>>>(R, W, d, scal, Bi);
  k_gemm<<<(N_DIM / 256) * (N_DIM / 256), 512, 0, stream>>>(Ai, Bi, scal, sA, C);
}

// Round 7
// 415.499 us; speedup vs baseline: 1.4371x; 1.0660x over previous
//
#include <hip/hip_runtime.h>

#define N_DIM 8192
#define E_DIM 4096
#define BK    128
#define NT    (E_DIM / BK)   // 32 K-tiles

using int4v  = __attribute__((ext_vector_type(4))) int;
using i32x16 = __attribute__((ext_vector_type(16))) int;

__device__ __forceinline__ void async16(const void* g, void* l) {
  __builtin_amdgcn_global_load_lds(
      (const __attribute__((address_space(1))) unsigned int*)g,
      (__attribute__((address_space(3))) unsigned int*)l, 16, 0, 0);
}

// ---- kernel 1: fused degree + per-row quantize of A + row-sum of ints ----
// wave per row; H read once into regs. qA = round(H*127/m_i); sA_i = d_i*m_i/127.
__global__ __launch_bounds__(256) void k_prepA(const float* __restrict__ H,
                                               const float* __restrict__ W,
                                               float* __restrict__ d,
                                               float* __restrict__ sA,
                                               int* __restrict__ rsA,
                                               signed char* __restrict__ A) {
  const int row  = blockIdx.x * 4 + (threadIdx.x >> 6);
  const int lane = threadIdx.x & 63;
  const float* hrow = H + (size_t)row * E_DIM;
  float4 h[16];
  float s = 0.f, m = 0.f;
#pragma unroll
  for (int i = 0; i < 16; ++i) {
    h[i] = *reinterpret_cast<const float4*>(hrow + lane * 4 + i * 256);
    float4 w = *reinterpret_cast<const float4*>(W + lane * 4 + i * 256);
    s += h[i].x * w.x + h[i].y * w.y + h[i].z * w.z + h[i].w * w.w;
    m = fmaxf(m, fmaxf(fmaxf(h[i].x, h[i].y), fmaxf(h[i].z, h[i].w)));
  }
#pragma unroll
  for (int off = 1; off < 64; off <<= 1) {
    s += __shfl_xor(s, off);
    m = fmaxf(m, __shfl_xor(m, off));
  }
  const float q = 127.0f / m;
  signed char* arow = A + (size_t)row * E_DIM;
  int rs = 0;
#pragma unroll
  for (int i = 0; i < 16; ++i) {
    const int b0 = __float2int_rn(h[i].x * q);
    const int b1 = __float2int_rn(h[i].y * q);
    const int b2 = __float2int_rn(h[i].z * q);
    const int b3 = __float2int_rn(h[i].w * q);
    rs += b0 + b1 + b2 + b3;
    const unsigned int pk = (unsigned)b0 | ((unsigned)b1 << 8) |
                            ((unsigned)b2 << 16) | ((unsigned)b3 << 24);
    *reinterpret_cast<unsigned int*>(arow + lane * 4 + i * 256) = pk;
  }
#pragma unroll
  for (int off = 1; off < 64; off <<= 1) rs += __shfl_xor(rs, off);
  if (lane == 0) {
    const float dv = rsqrtf(s);
    d[row]   = dv;
    sA[row]  = dv * m * (1.0f / 127.0f);
    rsA[row] = rs;
  }
}

// ---- kernel 1b: wmax (single block) -> scal[0] ----
__global__ __launch_bounds__(256) void k_wmax(const float* __restrict__ W,
                                              float* __restrict__ wmax) {
  __shared__ float red[4];
  float m = 0.f;
  for (int i = threadIdx.x; i < E_DIM; i += 256) m = fmaxf(m, W[i]);
#pragma unroll
  for (int off = 32; off; off >>= 1) m = fmaxf(m, __shfl_down(m, off));
  if ((threadIdx.x & 63) == 0) red[threadIdx.x >> 6] = m;
  __syncthreads();
  if (threadIdx.x == 0) wmax[0] = fmaxf(fmaxf(red[0], red[1]), fmaxf(red[2], red[3]));
}

// ---- kernel 3: Bt_i8[j][e] = round(W_e*R[e][j]*255/wmax) - 128 (d_j cancels) ----
// 128e x 128j tile; coalesced float4 reads; writer remapped (row = t>>1) for
// 128-B contiguous i8 stores; ft column reads conflict-free (stride 132).
__global__ __launch_bounds__(256) void k_makeB(const float* __restrict__ R,
                                               const float* __restrict__ W,
                                               const float* __restrict__ scal,
                                               signed char* __restrict__ Bt) {
  __shared__ float ft[128][132];
  __shared__ float wlds[128];
  const int j0 = blockIdx.x * 128;
  const int e0 = blockIdx.y * 128;
  const int t = threadIdx.x;
  const int c4 = (t & 31) * 4;
#pragma unroll
  for (int r = (t >> 5); r < 128; r += 8) {
    float4 v = *reinterpret_cast<const float4*>(&R[(size_t)(e0 + r) * N_DIM + j0 + c4]);
    *reinterpret_cast<float4*>(&ft[r][c4]) = v;
  }
  if (t < 128) wlds[t] = W[e0 + t] * (255.0f / scal[0]);
  __syncthreads();
  const int r = t >> 1, p = t & 1;          // output row (j-local), e-half
  union { signed char c[64]; int4v i4[4]; } o;
#pragma unroll
  for (int e = 0; e < 64; ++e) {
    const int ee = p * 64 + e;
    o.c[e] = (signed char)(__float2int_rn(ft[ee][r] * wlds[ee]) - 128);
  }
  signed char* dstp = Bt + (size_t)(j0 + r) * E_DIM + e0 + p * 64;
#pragma unroll
  for (int s2 = 0; s2 < 4; ++s2)
    *reinterpret_cast<int4v*>(dstp + s2 * 16) = o.i4[s2];
}

// ---- kernel 4: 256x256 i8 MFMA GEMM, tail-issued reads + stage-2-ahead ----
// Per phase: [STG; GATE; MM(p); RD(p+1); barrier]. Reads for p+1 overlap MM(p).
// Seals: A0',B0' gated P2 (read tail-P3); A1' gated P3 (read tail-P0);
// B1' gated P0(next) (read tail-P1). STG->region last-read gap >= 5 barriers.
// Registers: tail-reads reuse af0/af1/bf (WAR via issue order) -> no extra VGPR.
__global__ __launch_bounds__(512, 2) void k_gemm(const signed char* __restrict__ A,
                                                 const signed char* __restrict__ B,
                                                 const float* __restrict__ scal,
                                                 const float* __restrict__ sA,
                                                 const int* __restrict__ rsA,
                                                 const float* __restrict__ d,
                                                 float* __restrict__ C) {
  __shared__ alignas(16) signed char lds[131072];  // A: 2x32KB, B: 2x32KB

  const int bid   = blockIdx.x;          // 1024 blocks, %8==0 -> bijective swizzle
  const int chunk = gridDim.x >> 3;
  const int swzb  = (bid & 7) * chunk + (bid >> 3);
  const int tm = swzb >> 5, tn = swzb & 31;
  const size_t rowBase = (size_t)tm * 256;
  const size_t colBase = (size_t)tn * 256;

  const int t = threadIdx.x, wid = t >> 6, lane = t & 63;
  const int l31 = lane & 31, hi32 = lane >> 5;

  const signed char *pA0[2], *pA1[2], *pB0[2], *pB1[2];
#pragma unroll
  for (int j = 0; j < 2; ++j) {
    const int P  = j * 8192 + wid * 1024 + lane * 16;  // byte off in 16KB half
    const int rP = P >> 7;                             // row 0..127
    const int ce = (P ^ ((rP & 7) << 4)) & 127;        // pre-swizzled source col
    pA0[j] = A + (rowBase +       rP) * E_DIM + ce;
    pA1[j] = A + (rowBase + 128 + rP) * E_DIM + ce;
    pB0[j] = B + (colBase +       rP) * E_DIM + ce;
    pB1[j] = B + (colBase + 128 + rP) * E_DIM + ce;
  }
  const int dstw = wid * 1024;

#define STG(Pj, base_, kt)                                            \
  do {                                                                \
    async16(Pj[0] + (size_t)(kt) * BK, &lds[(base_) + dstw]);         \
    async16(Pj[1] + (size_t)(kt) * BK, &lds[(base_) + 8192 + dstw]);  \
  } while (0)

  const int rowAoff = ((wid & 3) * 32 + l31) * 128;
  const int rowBoff = ((wid >> 2) * 64 + l31) * 128;
  const int swz = (lane & 7) << 4;
  int colX[4];
#pragma unroll
  for (int k = 0; k < 4; ++k) colX[k] = (k * 32 + hi32 * 16) ^ swz;

  int4v af0[4], af1[4], bf[2][4];
  i32x16 acc[2][2][2] = {};  // [a-half][b-half][n]

#define RD_A(dst_, aH, cb)                                                        \
  do {                                                                            \
    _Pragma("unroll") for (int k = 0; k < 4; ++k)                                 \
      dst_[k] = *(const int4v*)&lds[(cb) * 32768 + (aH) * 16384 + rowAoff + colX[k]]; \
  } while (0)
#define RD_B(bH, cb)                                                              \
  do {                                                                            \
    _Pragma("unroll") for (int n = 0; n < 2; ++n)                                 \
      _Pragma("unroll") for (int k = 0; k < 4; ++k)                               \
        bf[n][k] = *(const int4v*)&lds[65536 + (cb) * 32768 + (bH) * 16384 +      \
                                       rowBoff + n * 4096 + colX[k]];             \
  } while (0)
#define MM(src_, a_, b_)                                                          \
  do {                                                                            \
    __builtin_amdgcn_s_setprio(1);                                                \
    _Pragma("unroll") for (int n = 0; n < 2; ++n)                                 \
      _Pragma("unroll") for (int k = 0; k < 4; ++k)                               \
        acc[a_][b_][n] =                                                          \
            __builtin_amdgcn_mfma_i32_32x32x32_i8(src_[k], bf[n][k],              \
                                                  acc[a_][b_][n], 0, 0, 0);       \
    __builtin_amdgcn_s_setprio(0);                                                \
  } while (0)
#define GATE(n_) asm volatile("s_waitcnt vmcnt(" #n_ ")" ::: "memory")

  // ---- prologue: stage ALL of tile 0, drain, seal, pre-read af0/bf0 ----
  STG(pA0, 0, 0);
  STG(pB0, 65536, 0);
  STG(pA1, 16384, 0);
  STG(pB1, 65536 + 16384, 0);
  GATE(0);
  __builtin_amdgcn_s_barrier();
  RD_A(af0, 0, 0);
  RD_B(0, 0);

  for (int T = 0; T < NT - 1; ++T) {
    const int c = T & 1, cN = c ^ 1;
    const int aN = cN * 32768, bN = 65536 + cN * 32768;

    // P0: stage A0(T+1); gate -> B1(T) landed; Q00; tail-read af1(T)
    STG(pA0, aN, T + 1);
    GATE(2);
    MM(af0, 0, 0);
    RD_A(af1, 1, c);
    __builtin_amdgcn_s_barrier();

    // P1: stage B0(T+1); Q10; tail-read bf1(T)
    STG(pB0, bN, T + 1);
    MM(af1, 1, 0);
    RD_B(1, c);
    __builtin_amdgcn_s_barrier();

    // P2: stage A1(T+1); gate -> A0,B0(T+1) landed; Q11
    STG(pA1, aN + 16384, T + 1);
    GATE(2);
    MM(af1, 1, 1);
    __builtin_amdgcn_s_barrier();

    // P3: stage B1(T+1); gate -> A1(T+1) landed; Q01; tail-read af0/bf0(T+1)
    STG(pB1, bN + 16384, T + 1);
    GATE(2);
    MM(af0, 0, 1);
    RD_A(af0, 0, cN);
    RD_B(0, cN);
    __builtin_amdgcn_s_barrier();
  }

  // ---- tail tile (buf 1): outstanding = B1(last) only ----
  GATE(0);
  MM(af0, 0, 0);
  RD_A(af1, 1, 1);
  __builtin_amdgcn_s_barrier();
  MM(af1, 1, 0);
  RD_B(1, 1);
  __builtin_amdgcn_s_barrier();
  MM(af1, 1, 1);
  MM(af0, 0, 1);
#undef STG
#undef RD_A
#undef RD_B
#undef MM
#undef GATE

  // ---- epilogue: C = sA[row]*(d[col]*wmax/255)*(acc + 128*rsA[row]) ----
  const float s2 = scal[0] * (1.0f / 255.0f);
  float dc[2][2];
#pragma unroll
  for (int b = 0; b < 2; ++b)
#pragma unroll
    for (int n = 0; n < 2; ++n)
      dc[b][n] = d[colBase + b * 128 + (wid >> 2) * 64 + n * 32 + l31] * s2;
#pragma unroll
  for (int a = 0; a < 2; ++a)
#pragma unroll
    for (int r = 0; r < 16; ++r) {
      const size_t row = rowBase + a * 128 + (wid & 3) * 32 + (r & 3) + 8 * (r >> 2) + 4 * hi32;
      const float fr = sA[row];
      const float rt = 128.0f * (float)rsA[row];
#pragma unroll
      for (int b = 0; b < 2; ++b)
#pragma unroll
        for (int n = 0; n < 2; ++n) {
          const size_t col = colBase + b * 128 + (wid >> 2) * 64 + n * 32 + l31;
          C[row * N_DIM + col] = fr * dc[b][n] * ((float)acc[a][b][n][r] + rt);
        }
    }
}

extern "C" void kernel_launch(void* const* d_in, const int* in_sizes, int n_in,
                              void* d_out, int out_size, void* d_ws, size_t ws_size,
                              hipStream_t stream) {
  const float* H = (const float*)d_in[0];   // [N, E]
  const float* R = (const float*)d_in[1];   // [E, N]
  const float* W = (const float*)d_in[2];   // [E]
  float* C = (float*)d_out;                 // [N, N]

  char* ws = (char*)d_ws;
  float* scal = (float*)ws;                              // [0]=wmax
  float* d    = (float*)(ws + 4096);                     // 32 KB
  float* sA   = (float*)(ws + 4096 + 32768);             // 32 KB
  int*   rsA  = (int*)  (ws + 4096 + 65536);             // 32 KB
  signed char* Ai = (signed char*)(ws + 131072);         // 32 MB
  signed char* Bi = Ai + (size_t)N_DIM * E_DIM;          // 32 MB

  k_prepA<<<N_DIM / 4, 256, 0, stream>>>(H, W, d, sA, rsA, Ai);
  k_wmax<<<1, 256, 0, stream>>>(W, scal);
  k_makeB<<<dim3(N_DIM / 128, E_DIM / 128), 256, 0, stream>>>(R, W, scal, Bi);
  k_gemm<<<(N_DIM / 256) * (N_DIM / 256), 512, 0, stream>>>(Ai, Bi, scal, sA, rsA, d, C);
}